// Round 13
// baseline (50.006 us; speedup 1.0000x reference)
//
#include <hip/hip_runtime.h>
#include <hip/hip_bf16.h>

typedef __attribute__((ext_vector_type(8))) short bf16x8;
typedef __attribute__((ext_vector_type(4))) float f32x4;

#define NB 32
#define NO 256
#define XS_BYTES (6 * 30 * 512)   // 92160 B x-slab (6 rows x 30 cols x 256ch bf16)

static __device__ __forceinline__ void gld16(const void* g, void* l) {
    __builtin_amdgcn_global_load_lds(
        (const __attribute__((address_space(1))) void*)g,
        (__attribute__((address_space(3))) void*)l, 16, 0, 0);
}

// Fused prep: blocks [0,288) build wrt; blocks [288, 288+3840) build xp.
// wrt layout, groups of 8 shorts: [s=tap*4+ic][kw2][mw][mf][klo][kcol][e8]
// -> per (step, wave=kw2*4+mw) one contiguous 4096B block, lane-linear.
__global__ void prep_kernel(const float* __restrict__ w2, __hip_bfloat16* __restrict__ wrt,
                            const float* __restrict__ x, __hip_bfloat16* __restrict__ xp) {
    if (blockIdx.x < 288) {
        int idx = blockIdx.x * 256 + threadIdx.x;   // group id in [0, 73728)
        int kcol = idx & 15;
        int klo = (idx >> 4) & 3;
        int mf = (idx >> 6) & 3;
        int mw = (idx >> 8) & 3;
        int kw2 = (idx >> 10) & 1;
        int s = idx >> 11;            // 0..35
        int tap = s >> 2;
        int ic = s & 3;
        int o = mw * 64 + mf * 16 + kcol;
        int ch = kw2 * 128 + ic * 32 + klo * 8;
        const float* src = w2 + (size_t)o * 2304 + (size_t)ch * 9 + tap;
        union { bf16x8 v; __hip_bfloat16 e[8]; } u;
#pragma unroll
        for (int e = 0; e < 8; ++e) u.e[e] = __float2bfloat16(src[e * 9]);
        *(bf16x8*)((short*)wrt + (size_t)idx * 8) = u.v;
        return;
    }
    __shared__ float tile[64][29];
    int blk = blockIdx.x - 288;
    int icnk = blk & 3;
    int t = blk >> 2;
    int pr = t % 30;
    int b = t / 30;
    int i0 = icnk * 64;
    __hip_bfloat16* dst = xp + ((size_t)(b * 30 + pr) * 30) * 256 + i0;
    const bf16x8 z = (bf16x8){0, 0, 0, 0, 0, 0, 0, 0};
    if (pr == 0 || pr == 29) {
        for (int e = threadIdx.x; e < 30 * 8; e += 256) {
            int q = e >> 3, part = e & 7;
            *(bf16x8*)((short*)(dst + (size_t)q * 256) + part * 8) = z;
        }
        return;
    }
    int p = pr - 1;
    for (int e = threadIdx.x; e < 64 * 28; e += 256) {
        int ii = e / 28, q = e % 28;
        tile[ii][q] = x[((b * 256 + i0 + ii) * 28 + p) * 28 + q];
    }
    __syncthreads();
    for (int e = threadIdx.x; e < 28 * 64; e += 256) {
        int q = e >> 6, ii = e & 63;
        dst[(size_t)(q + 1) * 256 + ii] = __float2bfloat16(tile[ii][q]);
    }
    if (threadIdx.x < 16) {
        int col = (threadIdx.x >> 3) * 29, part = threadIdx.x & 7;
        *(bf16x8*)((short*)(dst + (size_t)col * 256) + part * 8) = z;
    }
}

#define MM(A_, B_, mf_, nf_) \
    acc[mf_][nf_] = __builtin_amdgcn_mfma_f32_16x16x32_bf16(A_, B_, acc[mf_][nf_], 0, 0, 0);

#define CLUSTER(A0, A1, A2, A3, B0, B1, B2, B3, B4, B5, B6)             \
    __builtin_amdgcn_s_setprio(1);                                      \
    MM(A0, B0, 0, 0) MM(A1, B0, 1, 0) MM(A2, B0, 2, 0) MM(A3, B0, 3, 0) \
    MM(A0, B1, 0, 1) MM(A1, B1, 1, 1) MM(A2, B1, 2, 1) MM(A3, B1, 3, 1) \
    MM(A0, B2, 0, 2) MM(A1, B2, 1, 2) MM(A2, B2, 2, 2) MM(A3, B2, 3, 2) \
    MM(A0, B3, 0, 3) MM(A1, B3, 1, 3) MM(A2, B3, 2, 3) MM(A3, B3, 3, 3) \
    MM(A0, B4, 0, 4) MM(A1, B4, 1, 4) MM(A2, B4, 2, 4) MM(A3, B4, 3, 4) \
    MM(A0, B5, 0, 5) MM(A1, B5, 1, 5) MM(A2, B5, 2, 5) MM(A3, B5, 3, 5) \
    MM(A0, B6, 0, 6) MM(A1, B6, 1, 6) MM(A2, B6, 2, 6) MM(A3, B6, 3, 6) \
    __builtin_amdgcn_s_setprio(0);

#define LOADB(D0, D1, D2, D3, D4, D5, D6, XO)                                  \
    D0 = *(const bf16x8*)(Xs + ((u[0] ^ ((kk[0] & 7u) << 4)) ^ (XO)));         \
    D1 = *(const bf16x8*)(Xs + ((u[1] ^ ((kk[1] & 7u) << 4)) ^ (XO)));         \
    D2 = *(const bf16x8*)(Xs + ((u[2] ^ ((kk[2] & 7u) << 4)) ^ (XO)));         \
    D3 = *(const bf16x8*)(Xs + ((u[3] ^ ((kk[3] & 7u) << 4)) ^ (XO)));         \
    D4 = *(const bf16x8*)(Xs + ((u[4] ^ ((kk[4] & 7u) << 4)) ^ (XO)));         \
    D5 = *(const bf16x8*)(Xs + ((u[5] ^ ((kk[5] & 7u) << 4)) ^ (XO)));         \
    D6 = *(const bf16x8*)(Xs + ((u[6] ^ ((kk[6] & 7u) << 4)) ^ (XO)));

// Phase for step s = tap*4 + ICV (A-buffer parity ICV&1), B register ping-pong:
//  vmcnt(4) [stage(s) landed, stage(s+1) in flight] -> A(s) ds_read x4 ->
//  DMA stage(s+2) -> load B(s+1) into alternate regs -> sched_barrier ->
//  28-MFMA cluster consuming B(s) loaded one phase ago.
#define PHASE_E(ICV, XON)                                                     \
    {                                                                         \
        asm volatile("s_waitcnt vmcnt(4)" ::: "memory");                      \
        const char* ar = AbR + (((ICV) & 1) * 4096);                          \
        bf16x8 a0 = *(const bf16x8*)(ar);                                     \
        bf16x8 a1 = *(const bf16x8*)(ar + 1024);                              \
        bf16x8 a2 = *(const bf16x8*)(ar + 2048);                              \
        bf16x8 a3 = *(const bf16x8*)(ar + 3072);                              \
        char* l = AbW + (((ICV) & 1) * 4096);                                 \
        gld16(pG, l);                                                         \
        gld16(pG + 1024, l + 1024);                                           \
        gld16(pG + 2048, l + 2048);                                           \
        gld16(pG + 3072, l + 3072);                                           \
        pG += 32768;                                                          \
        LOADB(bn0, bn1, bn2, bn3, bn4, bn5, bn6, XON)                         \
        __builtin_amdgcn_sched_barrier(0);                                    \
        CLUSTER(a0, a1, a2, a3, bc0, bc1, bc2, bc3, bc4, bc5, bc6)            \
    }
#define PHASE_O(ICV, XON)                                                     \
    {                                                                         \
        asm volatile("s_waitcnt vmcnt(4)" ::: "memory");                      \
        const char* ar = AbR + (((ICV) & 1) * 4096);                          \
        bf16x8 a0 = *(const bf16x8*)(ar);                                     \
        bf16x8 a1 = *(const bf16x8*)(ar + 1024);                              \
        bf16x8 a2 = *(const bf16x8*)(ar + 2048);                              \
        bf16x8 a3 = *(const bf16x8*)(ar + 3072);                              \
        char* l = AbW + (((ICV) & 1) * 4096);                                 \
        gld16(pG, l);                                                         \
        gld16(pG + 1024, l + 1024);                                           \
        gld16(pG + 2048, l + 2048);                                           \
        gld16(pG + 3072, l + 3072);                                           \
        pG += 32768;                                                          \
        LOADB(bc0, bc1, bc2, bc3, bc4, bc5, bc6, XON)                         \
        __builtin_amdgcn_sched_barrier(0);                                    \
        CLUSTER(a0, a1, a2, a3, bn0, bn1, bn2, bn3, bn4, bn5, bn6)            \
    }

// Implicit-GEMM conv. 224 blocks (XCD-swizzled), 512 thr = 8 waves = (kw2*4+mw).
// Wave: 64 o x 112 n x its 128-ch half. Zero barriers in K-loop; A via per-wave
// global_load_lds double-buffer ring (depth 2, counted vmcnt); B via register
// ping-pong. NEW: per-wave s_sleep stagger so SIMD-mates run anti-phase
// (load segment of one overlaps MFMA cluster of the other).
__global__ __launch_bounds__(512, 2) void conv_kernel(
    const __hip_bfloat16* __restrict__ xp, const __hip_bfloat16* __restrict__ wrt,
    const float* __restrict__ xg, const float* __restrict__ w1,
    const float* __restrict__ b1, float* __restrict__ out) {
    __shared__ __align__(16) char Xs[XS_BYTES];      // 92160
    __shared__ __align__(16) char Ab[8 * 2 * 4096];  // 65536
    __shared__ float hsm[512];                       // 2048  -> 159744 total
    const int bid = blockIdx.x;
    const int v = (bid & 7) * 28 + (bid >> 3);   // bijective XCD swizzle (224 % 8 == 0)
    const int b = v / 7;
    const int nt = v - b * 7;
    const int tid = threadIdx.x;
    const int lane = tid & 63;
    const int wv = tid >> 6;
    const int mw = wv & 3;
    const int kw2 = wv >> 2;
    const int kcol = lane & 15;
    const int klo = lane >> 4;

    const char* wrtc = (const char*)wrt;
    char* AbW = Ab + wv * 8192;                  // wave-uniform DMA dest base
    const char* AbR = Ab + wv * 8192 + lane * 16;
    const char* pG = wrtc + wv * 4096 + lane * 16;

    // stage steps 0 and 1 into buf0/buf1 (drained by the prologue __syncthreads)
    gld16(pG, AbW);
    gld16(pG + 1024, AbW + 1024);
    gld16(pG + 2048, AbW + 2048);
    gld16(pG + 3072, AbW + 3072);
    pG += 32768;
    gld16(pG, AbW + 4096);
    gld16(pG + 1024, AbW + 4096 + 1024);
    gld16(pG + 2048, AbW + 4096 + 2048);
    gld16(pG + 3072, AbW + 4096 + 3072);
    pG += 32768;                                 // next staged step = 2

    // h[j] = sigmoid(xg[b].w1[j] + b1[j])
    {
        float s = b1[tid];
        const float* g = xg + b * 16;
        const float* w = w1 + tid * 16;
#pragma unroll
        for (int c = 0; c < 16; ++c) s += g[c] * w[c];
        hsm[tid] = 1.0f / (1.0f + expf(-s));
    }

    // stage x-slab: linear coalesced global read; 16B chunk w of position sp stored at
    // sp*512 + ((w ^ key(sp))<<4), key(sp) = (q + 4r)&7 (conflict-free, 4*30 == 0 mod 8).
    {
        const char* src = (const char*)(xp + ((size_t)b * 900 + nt * 120) * 256);
        for (int c = tid; c < 5760; c += 512) {
            int sp = c >> 5, w = c & 31;
            int rr = sp / 30;
            int qq = sp - rr * 30;
            int key = (qq + 4 * rr) & 7;
            *(bf16x8*)(Xs + sp * 512 + ((w ^ key) << 4)) = *(const bf16x8*)(src + (size_t)c * 16);
        }
    }
    __syncthreads();   // drains vmcnt(0) + lgkmcnt(0): steps 0/1 DMA and Xs all ready

    // ---- wave desync: stagger K-loop entry by wv*192 cyc so SIMD-mates are
    // anti-phase (robust to either w/2 or w%4 wave->SIMD mapping).
    for (int i = 0; i < wv; ++i) __builtin_amdgcn_s_sleep(3);

    // per-lane B geometry, incremental per-tap: u += dspv*512, kk += dkey
    unsigned u[7], kk[7];
#pragma unroll
    for (int nf = 0; nf < 7; ++nf) {
        int n = nf * 16 + kcol;
        int r0 = n / 28;
        int q0 = n - r0 * 28;
        u[nf] = (unsigned)((r0 * 30 + q0) * 512 + (klo << 4));
        kk[nf] = (unsigned)(q0 + 4 * r0);
    }
    const unsigned xo0 = (unsigned)((kw2 * 4 + 0) << 6);
    const unsigned xo1 = (unsigned)((kw2 * 4 + 1) << 6);
    const unsigned xo2 = (unsigned)((kw2 * 4 + 2) << 6);
    const unsigned xo3 = (unsigned)((kw2 * 4 + 3) << 6);

    f32x4 acc[4][7];
#pragma unroll
    for (int mf = 0; mf < 4; ++mf)
#pragma unroll
        for (int nf = 0; nf < 7; ++nf) acc[mf][nf] = (f32x4){0.f, 0.f, 0.f, 0.f};

    bf16x8 bc0, bc1, bc2, bc3, bc4, bc5, bc6;
    bf16x8 bn0, bn1, bn2, bn3, bn4, bn5, bn6;
    LOADB(bc0, bc1, bc2, bc3, bc4, bc5, bc6, xo0)    // B(step 0)

    for (int tap = 0; tap < 9; ++tap) {
        PHASE_E(0, xo1)                   // consume bc/B(ic0), load bn=B(ic1)
        PHASE_O(1, xo2)                   // consume bn,       load bc=B(ic2)
        PHASE_E(2, xo3)                   // consume bc,       load bn=B(ic3)
        if (tap < 8) {                    // advance geometry before next-tap B load
            const int cross = (tap == 2 || tap == 5);
            const unsigned da = cross ? 28u * 512u : 512u;
            const unsigned dk = cross ? 2u : 1u;
#pragma unroll
            for (int nf = 0; nf < 7; ++nf) { u[nf] += da; kk[nf] += dk; }
        }
        PHASE_O(3, xo0)                   // consume bn, load bc=B(tap+1,ic0) (tap8: dead)
    }
    // tail DMA stages read dead bytes past wrt -- never consumed, drained below.

    // epilogue: combine k-halves through LDS (Xs is dead), 2 rounds of 2 m-frags.
    __syncthreads();
    float* Xf = (float*)Xs;
#pragma unroll
    for (int r2 = 0; r2 < 2; ++r2) {
        if (kw2 == 1) {
#pragma unroll
            for (int mfi = 0; mfi < 2; ++mfi) {
                const int mf = r2 * 2 + mfi;
#pragma unroll
                for (int nf = 0; nf < 7; ++nf) {
#pragma unroll
                    for (int rr = 0; rr < 4; ++rr) {
                        int o = mw * 64 + mf * 16 + klo * 4 + rr;
                        int idx = (((mw * 2 + mfi) * 7 + nf) * 4 + rr) * 64 + lane;
                        Xf[idx] = hsm[2 * o + 1] * acc[mf][nf][rr];
                    }
                }
            }
        }
        __syncthreads();
        if (kw2 == 0) {
#pragma unroll
            for (int mfi = 0; mfi < 2; ++mfi) {
                const int mf = r2 * 2 + mfi;
#pragma unroll
                for (int nf = 0; nf < 7; ++nf) {
#pragma unroll
                    for (int rr = 0; rr < 4; ++rr) {
                        int o = mw * 64 + mf * 16 + klo * 4 + rr;
                        int idx = (((mw * 2 + mfi) * 7 + nf) * 4 + rr) * 64 + lane;
                        float y = hsm[2 * o] * acc[mf][nf][rr] + Xf[idx];
                        out[((size_t)b * NO + o) * 784 + nt * 112 + nf * 16 + kcol] = y;
                    }
                }
            }
        }
        __syncthreads();
    }
}

extern "C" void kernel_launch(void* const* d_in, const int* in_sizes, int n_in,
                              void* d_out, int out_size, void* d_ws, size_t ws_size,
                              hipStream_t stream) {
    const float* x = (const float*)d_in[0];
    const float* xg = (const float*)d_in[1];
    const float* w1 = (const float*)d_in[2];
    const float* b1 = (const float*)d_in[3];
    const float* w2 = (const float*)d_in[4];
    float* out = (float*)d_out;

    char* ws = (char*)d_ws;
    __hip_bfloat16* wrt = (__hip_bfloat16*)ws;                // 1,179,648 B
    __hip_bfloat16* xp = (__hip_bfloat16*)(ws + 1179648);     // 14,745,600 B (tail-stage overrun lands here harmlessly)

    prep_kernel<<<288 + NB * 30 * 4, 256, 0, stream>>>(w2, wrt, x, xp);
    conv_kernel<<<224, 512, 0, stream>>>(xp, wrt, xg, w1, b1, out);
}

// Round 14
// 49.719 us; speedup vs baseline: 1.0058x; 1.0058x over previous
//
#include <hip/hip_runtime.h>
#include <hip/hip_bf16.h>

typedef __attribute__((ext_vector_type(8))) short bf16x8;
typedef __attribute__((ext_vector_type(4))) float f32x4;

#define NB 32
#define NO 256
#define XS_BYTES (6 * 30 * 512)   // 92160 B x-slab

static __device__ __forceinline__ void gld16(const void* g, void* l) {
    __builtin_amdgcn_global_load_lds(
        (const __attribute__((address_space(1))) void*)g,
        (__attribute__((address_space(3))) void*)l, 16, 0, 0);
}

// Fused prep: blocks [0,288) build wrt; blocks [288, 288+3840) build xp.
// wrt layout, groups of 8 shorts: [s=tap*4+ic][kw2][mw][mf][klo][kcol][e8]
__global__ void prep_kernel(const float* __restrict__ w2, __hip_bfloat16* __restrict__ wrt,
                            const float* __restrict__ x, __hip_bfloat16* __restrict__ xp) {
    if (blockIdx.x < 288) {
        int idx = blockIdx.x * 256 + threadIdx.x;
        int kcol = idx & 15;
        int klo = (idx >> 4) & 3;
        int mf = (idx >> 6) & 3;
        int mw = (idx >> 8) & 3;
        int kw2 = (idx >> 10) & 1;
        int s = idx >> 11;
        int tap = s >> 2;
        int ic = s & 3;
        int o = mw * 64 + mf * 16 + kcol;
        int ch = kw2 * 128 + ic * 32 + klo * 8;
        const float* src = w2 + (size_t)o * 2304 + (size_t)ch * 9 + tap;
        union { bf16x8 v; __hip_bfloat16 e[8]; } u;
#pragma unroll
        for (int e = 0; e < 8; ++e) u.e[e] = __float2bfloat16(src[e * 9]);
        *(bf16x8*)((short*)wrt + (size_t)idx * 8) = u.v;
        return;
    }
    __shared__ float tile[64][29];
    int blk = blockIdx.x - 288;
    int icnk = blk & 3;
    int t = blk >> 2;
    int pr = t % 30;
    int b = t / 30;
    int i0 = icnk * 64;
    __hip_bfloat16* dst = xp + ((size_t)(b * 30 + pr) * 30) * 256 + i0;
    const bf16x8 z = (bf16x8){0, 0, 0, 0, 0, 0, 0, 0};
    if (pr == 0 || pr == 29) {
        for (int e = threadIdx.x; e < 30 * 8; e += 256) {
            int q = e >> 3, part = e & 7;
            *(bf16x8*)((short*)(dst + (size_t)q * 256) + part * 8) = z;
        }
        return;
    }
    int p = pr - 1;
    for (int e = threadIdx.x; e < 64 * 28; e += 256) {
        int ii = e / 28, q = e % 28;
        tile[ii][q] = x[((b * 256 + i0 + ii) * 28 + p) * 28 + q];
    }
    __syncthreads();
    for (int e = threadIdx.x; e < 28 * 64; e += 256) {
        int q = e >> 6, ii = e & 63;
        dst[(size_t)(q + 1) * 256 + ii] = __float2bfloat16(tile[ii][q]);
    }
    if (threadIdx.x < 16) {
        int col = (threadIdx.x >> 3) * 29, part = threadIdx.x & 7;
        *(bf16x8*)((short*)(dst + (size_t)col * 256) + part * 8) = z;
    }
}

#define MM(A_, B_, mf_, nf_) \
    acc[mf_][nf_] = __builtin_amdgcn_mfma_f32_16x16x32_bf16(A_, B_, acc[mf_][nf_], 0, 0, 0);

// H1: 16 MFMA (n-frags 0-3); H2: 12 MFMA (n-frags 4-6)
#define CL_H1(A0, A1, A2, A3, B0, B1, B2, B3)                           \
    __builtin_amdgcn_s_setprio(1);                                      \
    MM(A0, B0, 0, 0) MM(A1, B0, 1, 0) MM(A2, B0, 2, 0) MM(A3, B0, 3, 0) \
    MM(A0, B1, 0, 1) MM(A1, B1, 1, 1) MM(A2, B1, 2, 1) MM(A3, B1, 3, 1) \
    MM(A0, B2, 0, 2) MM(A1, B2, 1, 2) MM(A2, B2, 2, 2) MM(A3, B2, 3, 2) \
    MM(A0, B3, 0, 3) MM(A1, B3, 1, 3) MM(A2, B3, 2, 3) MM(A3, B3, 3, 3) \
    __builtin_amdgcn_s_setprio(0);
#define CL_H2(A0, A1, A2, A3, B4, B5, B6)                               \
    __builtin_amdgcn_s_setprio(1);                                      \
    MM(A0, B4, 0, 4) MM(A1, B4, 1, 4) MM(A2, B4, 2, 4) MM(A3, B4, 3, 4) \
    MM(A0, B5, 0, 5) MM(A1, B5, 1, 5) MM(A2, B5, 2, 5) MM(A3, B5, 3, 5) \
    MM(A0, B6, 0, 6) MM(A1, B6, 1, 6) MM(A2, B6, 2, 6) MM(A3, B6, 3, 6) \
    __builtin_amdgcn_s_setprio(0);

#define LOADB(D0, D1, D2, D3, D4, D5, D6, XO)                                  \
    D0 = *(const bf16x8*)(Xs + ((u[0] ^ ((kk[0] & 7u) << 4)) ^ (XO)));         \
    D1 = *(const bf16x8*)(Xs + ((u[1] ^ ((kk[1] & 7u) << 4)) ^ (XO)));         \
    D2 = *(const bf16x8*)(Xs + ((u[2] ^ ((kk[2] & 7u) << 4)) ^ (XO)));         \
    D3 = *(const bf16x8*)(Xs + ((u[3] ^ ((kk[3] & 7u) << 4)) ^ (XO)));         \
    D4 = *(const bf16x8*)(Xs + ((u[4] ^ ((kk[4] & 7u) << 4)) ^ (XO)));         \
    D5 = *(const bf16x8*)(Xs + ((u[5] ^ ((kk[5] & 7u) << 4)) ^ (XO)));         \
    D6 = *(const bf16x8*)(Xs + ((u[6] ^ ((kk[6] & 7u) << 4)) ^ (XO)));

// Fully-pipelined phase for step s (even phases consume set A / fill set B; odd
// phases the reverse; A(s+1) lives in buf[(s+1)&1]):
//   H1 (16 MFMA on current set)
//   vmcnt(4): stage(s+1) [issued 1.5 phases ago] landed; stage(s+2) in flight
//   ds_read A(s+1) x4 from buf[(s+1)&1]     -> consumed NEXT phase
//   DMA stage(s+3) into the same buffer      (WAR: ds_read issued first, ~400cy margin)
//   LOADB B(s+1)                              -> consumed NEXT phase
//   H2 (12 MFMA on current set)  -- loads land during H2 + next H1
#define PHASE_E(BUFOFF, XON)                                                  \
    {                                                                         \
        CL_H1(aA0, aA1, aA2, aA3, bA0, bA1, bA2, bA3)                         \
        asm volatile("s_waitcnt vmcnt(4)" ::: "memory");                      \
        aB0 = *(const bf16x8*)(AbR + (BUFOFF));                               \
        aB1 = *(const bf16x8*)(AbR + (BUFOFF) + 1024);                        \
        aB2 = *(const bf16x8*)(AbR + (BUFOFF) + 2048);                        \
        aB3 = *(const bf16x8*)(AbR + (BUFOFF) + 3072);                        \
        gld16(pG, AbW + (BUFOFF));                                            \
        gld16(pG + 1024, AbW + (BUFOFF) + 1024);                              \
        gld16(pG + 2048, AbW + (BUFOFF) + 2048);                              \
        gld16(pG + 3072, AbW + (BUFOFF) + 3072);                              \
        pG += 32768;                                                          \
        LOADB(bB0, bB1, bB2, bB3, bB4, bB5, bB6, XON)                         \
        __builtin_amdgcn_sched_barrier(0);                                    \
        CL_H2(aA0, aA1, aA2, aA3, bA4, bA5, bA6)                              \
    }
#define PHASE_O(BUFOFF, XON)                                                  \
    {                                                                         \
        CL_H1(aB0, aB1, aB2, aB3, bB0, bB1, bB2, bB3)                         \
        asm volatile("s_waitcnt vmcnt(4)" ::: "memory");                      \
        aA0 = *(const bf16x8*)(AbR + (BUFOFF));                               \
        aA1 = *(const bf16x8*)(AbR + (BUFOFF) + 1024);                        \
        aA2 = *(const bf16x8*)(AbR + (BUFOFF) + 2048);                        \
        aA3 = *(const bf16x8*)(AbR + (BUFOFF) + 3072);                        \
        gld16(pG, AbW + (BUFOFF));                                            \
        gld16(pG + 1024, AbW + (BUFOFF) + 1024);                              \
        gld16(pG + 2048, AbW + (BUFOFF) + 2048);                              \
        gld16(pG + 3072, AbW + (BUFOFF) + 3072);                              \
        pG += 32768;                                                          \
        LOADB(bA0, bA1, bA2, bA3, bA4, bA5, bA6, XON)                         \
        __builtin_amdgcn_sched_barrier(0);                                    \
        CL_H2(aB0, aB1, aB2, aB3, bB4, bB5, bB6)                              \
    }

// Implicit-GEMM conv. 224 blocks (XCD-swizzled), 512 thr = 8 waves = (kw2*4+mw).
// Wave: 64 o x 112 n x its 128-ch half. Zero barriers; depth-2 DMA A-ring;
// ALL loads consumed one phase after issue; waits buried mid-cluster.
__global__ __launch_bounds__(512, 2) void conv_kernel(
    const __hip_bfloat16* __restrict__ xp, const __hip_bfloat16* __restrict__ wrt,
    const float* __restrict__ xg, const float* __restrict__ w1,
    const float* __restrict__ b1, float* __restrict__ out) {
    __shared__ __align__(16) char Xs[XS_BYTES];      // 92160
    __shared__ __align__(16) char Ab[8 * 2 * 4096];  // 65536
    __shared__ float hsm[512];                       // 2048  -> 159744 total
    const int bid = blockIdx.x;
    const int v = (bid & 7) * 28 + (bid >> 3);   // bijective XCD swizzle (224 % 8 == 0)
    const int b = v / 7;
    const int nt = v - b * 7;
    const int tid = threadIdx.x;
    const int lane = tid & 63;
    const int wv = tid >> 6;
    const int mw = wv & 3;
    const int kw2 = wv >> 2;
    const int kcol = lane & 15;
    const int klo = lane >> 4;

    const char* wrtc = (const char*)wrt;
    char* AbW = Ab + wv * 8192;
    const char* AbR = Ab + wv * 8192 + lane * 16;
    const char* pG = wrtc + wv * 4096 + lane * 16;

    // stage steps 0 -> buf0, 1 -> buf1 (drained by prologue __syncthreads)
    gld16(pG, AbW);
    gld16(pG + 1024, AbW + 1024);
    gld16(pG + 2048, AbW + 2048);
    gld16(pG + 3072, AbW + 3072);
    pG += 32768;
    gld16(pG, AbW + 4096);
    gld16(pG + 1024, AbW + 4096 + 1024);
    gld16(pG + 2048, AbW + 4096 + 2048);
    gld16(pG + 3072, AbW + 4096 + 3072);
    pG += 32768;                                 // next staged step = 2

    // h[j] = sigmoid(xg[b].w1[j] + b1[j])
    {
        float s = b1[tid];
        const float* g = xg + b * 16;
        const float* w = w1 + tid * 16;
#pragma unroll
        for (int c = 0; c < 16; ++c) s += g[c] * w[c];
        hsm[tid] = 1.0f / (1.0f + expf(-s));
    }

    // stage x-slab (linear read, swizzled write; key=(q+4r)&7 conflict-free)
    {
        const char* src = (const char*)(xp + ((size_t)b * 900 + nt * 120) * 256);
        for (int c = tid; c < 5760; c += 512) {
            int sp = c >> 5, w = c & 31;
            int rr = sp / 30;
            int qq = sp - rr * 30;
            int key = (qq + 4 * rr) & 7;
            *(bf16x8*)(Xs + sp * 512 + ((w ^ key) << 4)) = *(const bf16x8*)(src + (size_t)c * 16);
        }
    }
    __syncthreads();   // drains: steps 0/1 DMA landed, Xs ready

    unsigned u[7], kk[7];
#pragma unroll
    for (int nf = 0; nf < 7; ++nf) {
        int n = nf * 16 + kcol;
        int r0 = n / 28;
        int q0 = n - r0 * 28;
        u[nf] = (unsigned)((r0 * 30 + q0) * 512 + (klo << 4));
        kk[nf] = (unsigned)(q0 + 4 * r0);
    }
    const unsigned xo0 = (unsigned)((kw2 * 4 + 0) << 6);
    const unsigned xo1 = (unsigned)((kw2 * 4 + 1) << 6);
    const unsigned xo2 = (unsigned)((kw2 * 4 + 2) << 6);
    const unsigned xo3 = (unsigned)((kw2 * 4 + 3) << 6);

    f32x4 acc[4][7];
#pragma unroll
    for (int mf = 0; mf < 4; ++mf)
#pragma unroll
        for (int nf = 0; nf < 7; ++nf) acc[mf][nf] = (f32x4){0.f, 0.f, 0.f, 0.f};

    bf16x8 aA0, aA1, aA2, aA3, aB0, aB1, aB2, aB3;
    bf16x8 bA0, bA1, bA2, bA3, bA4, bA5, bA6;
    bf16x8 bB0, bB1, bB2, bB3, bB4, bB5, bB6;

    // prologue: A(0) from buf0 into set A; re-arm buf0 with stage(2); B(0) into set A
    aA0 = *(const bf16x8*)(AbR);
    aA1 = *(const bf16x8*)(AbR + 1024);
    aA2 = *(const bf16x8*)(AbR + 2048);
    aA3 = *(const bf16x8*)(AbR + 3072);
    gld16(pG, AbW);
    gld16(pG + 1024, AbW + 1024);
    gld16(pG + 2048, AbW + 2048);
    gld16(pG + 3072, AbW + 3072);
    pG += 32768;                                 // next staged step = 3
    LOADB(bA0, bA1, bA2, bA3, bA4, bA5, bA6, xo0)

    for (int tap = 0; tap < 9; ++tap) {
        PHASE_E(4096, xo1)                // s%4==0: A(s+1) in buf1, stage->buf1
        PHASE_O(0, xo2)                   // s%4==1: buf0
        PHASE_E(4096, xo3)                // s%4==2: buf1
        if (tap < 8) {                    // advance geometry before next-tap B load
            const int cross = (tap == 2 || tap == 5);
            const unsigned da = cross ? 28u * 512u : 512u;
            const unsigned dk = cross ? 2u : 1u;
#pragma unroll
            for (int nf = 0; nf < 7; ++nf) { u[nf] += da; kk[nf] += dk; }
        }
        PHASE_O(0, xo0)                   // s%4==3: buf0; loads B(tap+1,ic0)
    }
    // tail stages read dead bytes past wrt (within ws) -- drained below, never consumed.

    // epilogue: combine k-halves through LDS (Xs dead), 2 rounds of 2 m-frags.
    __syncthreads();
    float* Xf = (float*)Xs;
#pragma unroll
    for (int r2 = 0; r2 < 2; ++r2) {
        if (kw2 == 1) {
#pragma unroll
            for (int mfi = 0; mfi < 2; ++mfi) {
                const int mf = r2 * 2 + mfi;
#pragma unroll
                for (int nf = 0; nf < 7; ++nf) {
#pragma unroll
                    for (int rr = 0; rr < 4; ++rr) {
                        int o = mw * 64 + mf * 16 + klo * 4 + rr;
                        int idx = (((mw * 2 + mfi) * 7 + nf) * 4 + rr) * 64 + lane;
                        Xf[idx] = hsm[2 * o + 1] * acc[mf][nf][rr];
                    }
                }
            }
        }
        __syncthreads();
        if (kw2 == 0) {
#pragma unroll
            for (int mfi = 0; mfi < 2; ++mfi) {
                const int mf = r2 * 2 + mfi;
#pragma unroll
                for (int nf = 0; nf < 7; ++nf) {
#pragma unroll
                    for (int rr = 0; rr < 4; ++rr) {
                        int o = mw * 64 + mf * 16 + klo * 4 + rr;
                        int idx = (((mw * 2 + mfi) * 7 + nf) * 4 + rr) * 64 + lane;
                        float y = hsm[2 * o] * acc[mf][nf][rr] + Xf[idx];
                        out[((size_t)b * NO + o) * 784 + nt * 112 + nf * 16 + kcol] = y;
                    }
                }
            }
        }
        __syncthreads();
    }
}

extern "C" void kernel_launch(void* const* d_in, const int* in_sizes, int n_in,
                              void* d_out, int out_size, void* d_ws, size_t ws_size,
                              hipStream_t stream) {
    const float* x = (const float*)d_in[0];
    const float* xg = (const float*)d_in[1];
    const float* w1 = (const float*)d_in[2];
    const float* b1 = (const float*)d_in[3];
    const float* w2 = (const float*)d_in[4];
    float* out = (float*)d_out;

    char* ws = (char*)d_ws;
    __hip_bfloat16* wrt = (__hip_bfloat16*)ws;                // 1,179,648 B
    __hip_bfloat16* xp = (__hip_bfloat16*)(ws + 1179648);     // 14.7 MB (tail-stage overrun lands here)

    prep_kernel<<<288 + NB * 30 * 4, 256, 0, stream>>>(w2, wrt, x, xp);
    conv_kernel<<<224, 512, 0, stream>>>(xp, wrt, xg, w1, b1, out);
}

// Round 15
// 46.103 us; speedup vs baseline: 1.0847x; 1.0784x over previous
//
#include <hip/hip_runtime.h>
#include <hip/hip_bf16.h>

typedef __attribute__((ext_vector_type(8))) short bf16x8;
typedef __attribute__((ext_vector_type(4))) float f32x4;

#define NB 32
#define NO 256
#define XS_BYTES (6 * 30 * 512)   // 92160 B x-slab

static __device__ __forceinline__ void gld16(const void* g, void* l) {
    __builtin_amdgcn_global_load_lds(
        (const __attribute__((address_space(1))) void*)g,
        (__attribute__((address_space(3))) void*)l, 16, 0, 0);
}

// prep: wrt only. Layout, groups of 8 shorts: [s=tap*4+ic][kw2][mw][mf][klo][kcol][e8]
__global__ void prep_kernel(const float* __restrict__ w2, __hip_bfloat16* __restrict__ wrt) {
    int idx = blockIdx.x * 256 + threadIdx.x;   // [0, 73728)
    int kcol = idx & 15;
    int klo = (idx >> 4) & 3;
    int mf = (idx >> 6) & 3;
    int mw = (idx >> 8) & 3;
    int kw2 = (idx >> 10) & 1;
    int s = idx >> 11;
    int tap = s >> 2;
    int ic = s & 3;
    int o = mw * 64 + mf * 16 + kcol;
    int ch = kw2 * 128 + ic * 32 + klo * 8;
    const float* src = w2 + (size_t)o * 2304 + (size_t)ch * 9 + tap;
    union { bf16x8 v; __hip_bfloat16 e[8]; } u;
#pragma unroll
    for (int e = 0; e < 8; ++e) u.e[e] = __float2bfloat16(src[e * 9]);
    *(bf16x8*)((short*)wrt + (size_t)idx * 8) = u.v;
}

#define MM(A_, B_, mf_, nf_) \
    acc[mf_][nf_] = __builtin_amdgcn_mfma_f32_16x16x32_bf16(A_, B_, acc[mf_][nf_], 0, 0, 0);

#define CL_H1(A0, A1, A2, A3, B0, B1, B2, B3)                           \
    __builtin_amdgcn_s_setprio(1);                                      \
    MM(A0, B0, 0, 0) MM(A1, B0, 1, 0) MM(A2, B0, 2, 0) MM(A3, B0, 3, 0) \
    MM(A0, B1, 0, 1) MM(A1, B1, 1, 1) MM(A2, B1, 2, 1) MM(A3, B1, 3, 1) \
    MM(A0, B2, 0, 2) MM(A1, B2, 1, 2) MM(A2, B2, 2, 2) MM(A3, B2, 3, 2) \
    MM(A0, B3, 0, 3) MM(A1, B3, 1, 3) MM(A2, B3, 2, 3) MM(A3, B3, 3, 3) \
    __builtin_amdgcn_s_setprio(0);
#define CL_H2(A0, A1, A2, A3, B4, B5, B6)                               \
    __builtin_amdgcn_s_setprio(1);                                      \
    MM(A0, B4, 0, 4) MM(A1, B4, 1, 4) MM(A2, B4, 2, 4) MM(A3, B4, 3, 4) \
    MM(A0, B5, 0, 5) MM(A1, B5, 1, 5) MM(A2, B5, 2, 5) MM(A3, B5, 3, 5) \
    MM(A0, B6, 0, 6) MM(A1, B6, 1, 6) MM(A2, B6, 2, 6) MM(A3, B6, 3, 6) \
    __builtin_amdgcn_s_setprio(0);

#define LOADB(D0, D1, D2, D3, D4, D5, D6, XO)                                  \
    D0 = *(const bf16x8*)(Xs + ((u[0] ^ ((kk[0] & 7u) << 4)) ^ (XO)));         \
    D1 = *(const bf16x8*)(Xs + ((u[1] ^ ((kk[1] & 7u) << 4)) ^ (XO)));         \
    D2 = *(const bf16x8*)(Xs + ((u[2] ^ ((kk[2] & 7u) << 4)) ^ (XO)));         \
    D3 = *(const bf16x8*)(Xs + ((u[3] ^ ((kk[3] & 7u) << 4)) ^ (XO)));         \
    D4 = *(const bf16x8*)(Xs + ((u[4] ^ ((kk[4] & 7u) << 4)) ^ (XO)));         \
    D5 = *(const bf16x8*)(Xs + ((u[5] ^ ((kk[5] & 7u) << 4)) ^ (XO)));         \
    D6 = *(const bf16x8*)(Xs + ((u[6] ^ ((kk[6] & 7u) << 4)) ^ (XO)));

// Pipelined phase (identical to r14, verified): H1 -> {vmcnt(4), A(s+1) ds_read,
// DMA stage(s+3), LOADB B(s+1)} -> H2. All loads consumed one phase after issue.
#define PHASE_E(BUFOFF, XON)                                                  \
    {                                                                         \
        CL_H1(aA0, aA1, aA2, aA3, bA0, bA1, bA2, bA3)                         \
        asm volatile("s_waitcnt vmcnt(4)" ::: "memory");                      \
        aB0 = *(const bf16x8*)(AbR + (BUFOFF));                               \
        aB1 = *(const bf16x8*)(AbR + (BUFOFF) + 1024);                        \
        aB2 = *(const bf16x8*)(AbR + (BUFOFF) + 2048);                        \
        aB3 = *(const bf16x8*)(AbR + (BUFOFF) + 3072);                        \
        gld16(pG, AbW + (BUFOFF));                                            \
        gld16(pG + 1024, AbW + (BUFOFF) + 1024);                              \
        gld16(pG + 2048, AbW + (BUFOFF) + 2048);                              \
        gld16(pG + 3072, AbW + (BUFOFF) + 3072);                              \
        pG += 32768;                                                          \
        LOADB(bB0, bB1, bB2, bB3, bB4, bB5, bB6, XON)                         \
        __builtin_amdgcn_sched_barrier(0);                                    \
        CL_H2(aA0, aA1, aA2, aA3, bA4, bA5, bA6)                              \
    }
#define PHASE_O(BUFOFF, XON)                                                  \
    {                                                                         \
        CL_H1(aB0, aB1, aB2, aB3, bB0, bB1, bB2, bB3)                         \
        asm volatile("s_waitcnt vmcnt(4)" ::: "memory");                      \
        aA0 = *(const bf16x8*)(AbR + (BUFOFF));                               \
        aA1 = *(const bf16x8*)(AbR + (BUFOFF) + 1024);                        \
        aA2 = *(const bf16x8*)(AbR + (BUFOFF) + 2048);                        \
        aA3 = *(const bf16x8*)(AbR + (BUFOFF) + 3072);                        \
        gld16(pG, AbW + (BUFOFF));                                            \
        gld16(pG + 1024, AbW + (BUFOFF) + 1024);                              \
        gld16(pG + 2048, AbW + (BUFOFF) + 2048);                              \
        gld16(pG + 3072, AbW + (BUFOFF) + 3072);                              \
        pG += 32768;                                                          \
        LOADB(bA0, bA1, bA2, bA3, bA4, bA5, bA6, XON)                         \
        __builtin_amdgcn_sched_barrier(0);                                    \
        CL_H2(aB0, aB1, aB2, aB3, bB4, bB5, bB6)                              \
    }

// Implicit-GEMM conv, now staging DIRECTLY from x (fp32 NCHW) with in-kernel
// transpose+cvt+swizzle -- the xp intermediate (29 MB of HBM traffic) is gone.
__global__ __launch_bounds__(512, 2) void conv_kernel(
    const float* __restrict__ x, const __hip_bfloat16* __restrict__ wrt,
    const float* __restrict__ xg, const float* __restrict__ w1,
    const float* __restrict__ b1, float* __restrict__ out) {
    __shared__ __align__(16) char Xs[XS_BYTES];      // 92160
    __shared__ __align__(16) char Ab[8 * 2 * 4096];  // 65536
    __shared__ float hsm[512];                       // 2048  -> 159744 total
    const int bid = blockIdx.x;
    const int v = (bid & 7) * 28 + (bid >> 3);   // bijective XCD swizzle (224 % 8 == 0)
    const int b = v / 7;
    const int nt = v - b * 7;
    const int tid = threadIdx.x;
    const int lane = tid & 63;
    const int wv = tid >> 6;
    const int mw = wv & 3;
    const int kw2 = wv >> 2;
    const int kcol = lane & 15;
    const int klo = lane >> 4;

    const char* wrtc = (const char*)wrt;
    char* AbW = Ab + wv * 8192;
    const char* AbR = Ab + wv * 8192 + lane * 16;
    const char* pG = wrtc + wv * 4096 + lane * 16;

    // stage A steps 0 -> buf0, 1 -> buf1 (drained by prologue __syncthreads)
    gld16(pG, AbW);
    gld16(pG + 1024, AbW + 1024);
    gld16(pG + 2048, AbW + 2048);
    gld16(pG + 3072, AbW + 3072);
    pG += 32768;
    gld16(pG, AbW + 4096);
    gld16(pG + 1024, AbW + 4096 + 1024);
    gld16(pG + 2048, AbW + 4096 + 2048);
    gld16(pG + 3072, AbW + 4096 + 3072);
    pG += 32768;                                 // next staged step = 2

    // h[j] = sigmoid(xg[b].w1[j] + b1[j])
    {
        float s = b1[tid];
        const float* g = xg + b * 16;
        const float* w = w1 + tid * 16;
#pragma unroll
        for (int c = 0; c < 16; ++c) s += g[c] * w[c];
        hsm[tid] = 1.0f / (1.0f + expf(-s));
    }

    // ---- x-slab staging straight from x (fp32 NCHW), fused transpose+cvt+swizzle.
    // Writer layout == r14's verified reader algebra: position sp holds chunk
    // w=ch>>3 at sp*512 + ((w ^ key(sp))<<4) + (ch&7)*2, key(sp)=(q+4r)&7.
    {
        const bf16x8 z = (bf16x8){0, 0, 0, 0, 0, 0, 0, 0};
        // zero pad cols 0/29 (all rows, all 32 phys chunks)
        for (int e = tid; e < 6 * 2 * 32; e += 512) {
            int w = e & 31;
            int t2 = e >> 5;
            int row = t2 >> 1;
            int col = (t2 & 1) ? 29 : 0;
            *(bf16x8*)(Xs + (row * 30 + col) * 512 + w * 16) = z;
        }
        // zero pad rows (nt==0: slab row 0; nt==6: slab row 5)
        if (nt == 0) {
            for (int e = tid; e < 30 * 32; e += 512)
                *(bf16x8*)(Xs + (e >> 5) * 512 + (e & 31) * 16) = z;
        }
        if (nt == 6) {
            for (int e = tid; e < 30 * 32; e += 512)
                *(bf16x8*)(Xs + (150 + (e >> 5)) * 512 + (e & 31) * 16) = z;
        }
        // interior: e -> (pair = ch*? , c4): pair-major for coalesced float4 reads
        const int p0 = nt * 4 - 1;
        const float* xb = x + (size_t)b * 256 * 784;
        for (int e = tid; e < 1536 * 7; e += 512) {
            int c4 = e % 7;
            int pair = e / 7;
            int ch = pair & 255;
            int row = pair >> 8;
            int p = p0 + row;
            if (p >= 0 && p < 28) {
                f32x4 val = *(const f32x4*)(xb + ((size_t)ch * 28 + p) * 28 + 4 * c4);
                int w = ch >> 3;
                int bi = (ch & 7) * 2;
                int spb = row * 30 + 4 * c4 + 1;
#pragma unroll
                for (int k = 0; k < 4; ++k) {
                    int sp = spb + k;
                    int key = ((4 * c4 + 1 + k) + 4 * row) & 7;
                    *(__hip_bfloat16*)(Xs + sp * 512 + (((w ^ key) << 4) | bi)) =
                        __float2bfloat16(val[k]);
                }
            }
        }
    }
    __syncthreads();   // drains: A steps 0/1 DMA landed, Xs ready

    unsigned u[7], kk[7];
#pragma unroll
    for (int nf = 0; nf < 7; ++nf) {
        int n = nf * 16 + kcol;
        int r0 = n / 28;
        int q0 = n - r0 * 28;
        u[nf] = (unsigned)((r0 * 30 + q0) * 512 + (klo << 4));
        kk[nf] = (unsigned)(q0 + 4 * r0);
    }
    const unsigned xo0 = (unsigned)((kw2 * 4 + 0) << 6);
    const unsigned xo1 = (unsigned)((kw2 * 4 + 1) << 6);
    const unsigned xo2 = (unsigned)((kw2 * 4 + 2) << 6);
    const unsigned xo3 = (unsigned)((kw2 * 4 + 3) << 6);

    f32x4 acc[4][7];
#pragma unroll
    for (int mf = 0; mf < 4; ++mf)
#pragma unroll
        for (int nf = 0; nf < 7; ++nf) acc[mf][nf] = (f32x4){0.f, 0.f, 0.f, 0.f};

    bf16x8 aA0, aA1, aA2, aA3, aB0, aB1, aB2, aB3;
    bf16x8 bA0, bA1, bA2, bA3, bA4, bA5, bA6;
    bf16x8 bB0, bB1, bB2, bB3, bB4, bB5, bB6;

    // prologue: A(0) from buf0; re-arm buf0 with stage(2); B(0)
    aA0 = *(const bf16x8*)(AbR);
    aA1 = *(const bf16x8*)(AbR + 1024);
    aA2 = *(const bf16x8*)(AbR + 2048);
    aA3 = *(const bf16x8*)(AbR + 3072);
    gld16(pG, AbW);
    gld16(pG + 1024, AbW + 1024);
    gld16(pG + 2048, AbW + 2048);
    gld16(pG + 3072, AbW + 3072);
    pG += 32768;                                 // next staged step = 3
    LOADB(bA0, bA1, bA2, bA3, bA4, bA5, bA6, xo0)

    for (int tap = 0; tap < 9; ++tap) {
        PHASE_E(4096, xo1)
        PHASE_O(0, xo2)
        PHASE_E(4096, xo3)
        if (tap < 8) {
            const int cross = (tap == 2 || tap == 5);
            const unsigned da = cross ? 28u * 512u : 512u;
            const unsigned dk = cross ? 2u : 1u;
#pragma unroll
            for (int nf = 0; nf < 7; ++nf) { u[nf] += da; kk[nf] += dk; }
        }
        PHASE_O(0, xo0)
    }
    // tail stages read dead bytes past wrt (within ws) -- drained below, never consumed.

    // epilogue: combine k-halves through LDS (Xs dead), 2 rounds of 2 m-frags.
    __syncthreads();
    float* Xf = (float*)Xs;
#pragma unroll
    for (int r2 = 0; r2 < 2; ++r2) {
        if (kw2 == 1) {
#pragma unroll
            for (int mfi = 0; mfi < 2; ++mfi) {
                const int mf = r2 * 2 + mfi;
#pragma unroll
                for (int nf = 0; nf < 7; ++nf) {
#pragma unroll
                    for (int rr = 0; rr < 4; ++rr) {
                        int o = mw * 64 + mf * 16 + klo * 4 + rr;
                        int idx = (((mw * 2 + mfi) * 7 + nf) * 4 + rr) * 64 + lane;
                        Xf[idx] = hsm[2 * o + 1] * acc[mf][nf][rr];
                    }
                }
            }
        }
        __syncthreads();
        if (kw2 == 0) {
#pragma unroll
            for (int mfi = 0; mfi < 2; ++mfi) {
                const int mf = r2 * 2 + mfi;
#pragma unroll
                for (int nf = 0; nf < 7; ++nf) {
#pragma unroll
                    for (int rr = 0; rr < 4; ++rr) {
                        int o = mw * 64 + mf * 16 + klo * 4 + rr;
                        int idx = (((mw * 2 + mfi) * 7 + nf) * 4 + rr) * 64 + lane;
                        float y = hsm[2 * o] * acc[mf][nf][rr] + Xf[idx];
                        out[((size_t)b * NO + o) * 784 + nt * 112 + nf * 16 + kcol] = y;
                    }
                }
            }
        }
        __syncthreads();
    }
}

extern "C" void kernel_launch(void* const* d_in, const int* in_sizes, int n_in,
                              void* d_out, int out_size, void* d_ws, size_t ws_size,
                              hipStream_t stream) {
    const float* x = (const float*)d_in[0];
    const float* xg = (const float*)d_in[1];
    const float* w1 = (const float*)d_in[2];
    const float* b1 = (const float*)d_in[3];
    const float* w2 = (const float*)d_in[4];
    float* out = (float*)d_out;

    char* ws = (char*)d_ws;
    __hip_bfloat16* wrt = (__hip_bfloat16*)ws;   // 1,179,648 B (A-ring tail overrun reads
                                                 //  land in the unused ws region after it)

    prep_kernel<<<288, 256, 0, stream>>>(w2, wrt);
    conv_kernel<<<224, 512, 0, stream>>>(x, wrt, xg, w1, b1, out);
}

// Round 16
// 44.111 us; speedup vs baseline: 1.1336x; 1.0452x over previous
//
#include <hip/hip_runtime.h>
#include <hip/hip_bf16.h>

typedef __attribute__((ext_vector_type(8))) short bf16x8;
typedef __attribute__((ext_vector_type(4))) short bf16x4;
typedef __attribute__((ext_vector_type(4))) float f32x4;

#define NB 32
#define NO 256

static __device__ __forceinline__ void gld16(const void* g, void* l) {
    __builtin_amdgcn_global_load_lds(
        (const __attribute__((address_space(1))) void*)g,
        (__attribute__((address_space(3))) void*)l, 16, 0, 0);
}

// prep: wrt only. Layout, groups of 8 shorts: [s=tap*4+ic][kw2][mw][mf][klo][kcol][e8]
__global__ void prep_kernel(const float* __restrict__ w2, __hip_bfloat16* __restrict__ wrt) {
    int idx = blockIdx.x * 256 + threadIdx.x;   // [0, 73728)
    int kcol = idx & 15;
    int klo = (idx >> 4) & 3;
    int mf = (idx >> 6) & 3;
    int mw = (idx >> 8) & 3;
    int kw2 = (idx >> 10) & 1;
    int s = idx >> 11;
    int tap = s >> 2;
    int ic = s & 3;
    int o = mw * 64 + mf * 16 + kcol;
    int ch = kw2 * 128 + ic * 32 + klo * 8;
    const float* src = w2 + (size_t)o * 2304 + (size_t)ch * 9 + tap;
    union { bf16x8 v; __hip_bfloat16 e[8]; } u;
#pragma unroll
    for (int e = 0; e < 8; ++e) u.e[e] = __float2bfloat16(src[e * 9]);
    *(bf16x8*)((short*)wrt + (size_t)idx * 8) = u.v;
}

#define MM(A_, B_, mf_, nf_) \
    acc[mf_][nf_] = __builtin_amdgcn_mfma_f32_16x16x32_bf16(A_, B_, acc[mf_][nf_], 0, 0, 0);

#define CL_H1(A0, A1, A2, A3, B0, B1, B2, B3)                           \
    __builtin_amdgcn_s_setprio(1);                                      \
    MM(A0, B0, 0, 0) MM(A1, B0, 1, 0) MM(A2, B0, 2, 0) MM(A3, B0, 3, 0) \
    MM(A0, B1, 0, 1) MM(A1, B1, 1, 1) MM(A2, B1, 2, 1) MM(A3, B1, 3, 1) \
    MM(A0, B2, 0, 2) MM(A1, B2, 1, 2) MM(A2, B2, 2, 2) MM(A3, B2, 3, 2) \
    MM(A0, B3, 0, 3) MM(A1, B3, 1, 3) MM(A2, B3, 2, 3) MM(A3, B3, 3, 3) \
    __builtin_amdgcn_s_setprio(0);
#define CL_H2(A0, A1, A2, A3, B4, B5, B6)                               \
    __builtin_amdgcn_s_setprio(1);                                      \
    MM(A0, B4, 0, 4) MM(A1, B4, 1, 4) MM(A2, B4, 2, 4) MM(A3, B4, 3, 4) \
    MM(A0, B5, 0, 5) MM(A1, B5, 1, 5) MM(A2, B5, 2, 5) MM(A3, B5, 3, 5) \
    MM(A0, B6, 0, 6) MM(A1, B6, 1, 6) MM(A2, B6, 2, 6) MM(A3, B6, 3, 6) \
    __builtin_amdgcn_s_setprio(0);

#define LOADB(D0, D1, D2, D3, D4, D5, D6, XO)                                  \
    D0 = *(const bf16x8*)(Xs + ((u[0] ^ ((kk[0] & 7u) << 4)) ^ (XO)));         \
    D1 = *(const bf16x8*)(Xs + ((u[1] ^ ((kk[1] & 7u) << 4)) ^ (XO)));         \
    D2 = *(const bf16x8*)(Xs + ((u[2] ^ ((kk[2] & 7u) << 4)) ^ (XO)));         \
    D3 = *(const bf16x8*)(Xs + ((u[3] ^ ((kk[3] & 7u) << 4)) ^ (XO)));         \
    D4 = *(const bf16x8*)(Xs + ((u[4] ^ ((kk[4] & 7u) << 4)) ^ (XO)));         \
    D5 = *(const bf16x8*)(Xs + ((u[5] ^ ((kk[5] & 7u) << 4)) ^ (XO)));         \
    D6 = *(const bf16x8*)(Xs + ((u[6] ^ ((kk[6] & 7u) << 4)) ^ (XO)));

// Pipelined phase (identical to r14/r15, verified): H1 -> {vmcnt(4), A(s+1) ds_read,
// DMA stage(s+3), LOADB B(s+1)} -> H2. All loads consumed one phase after issue.
#define PHASE_E(BUFOFF, XON)                                                  \
    {                                                                         \
        CL_H1(aA0, aA1, aA2, aA3, bA0, bA1, bA2, bA3)                         \
        asm volatile("s_waitcnt vmcnt(4)" ::: "memory");                      \
        aB0 = *(const bf16x8*)(AbR + (BUFOFF));                               \
        aB1 = *(const bf16x8*)(AbR + (BUFOFF) + 1024);                        \
        aB2 = *(const bf16x8*)(AbR + (BUFOFF) + 2048);                        \
        aB3 = *(const bf16x8*)(AbR + (BUFOFF) + 3072);                        \
        gld16(pG, AbW + (BUFOFF));                                            \
        gld16(pG + 1024, AbW + (BUFOFF) + 1024);                              \
        gld16(pG + 2048, AbW + (BUFOFF) + 2048);                              \
        gld16(pG + 3072, AbW + (BUFOFF) + 3072);                              \
        pG += 32768;                                                          \
        LOADB(bB0, bB1, bB2, bB3, bB4, bB5, bB6, XON)                         \
        __builtin_amdgcn_sched_barrier(0);                                    \
        CL_H2(aA0, aA1, aA2, aA3, bA4, bA5, bA6)                              \
    }
#define PHASE_O(BUFOFF, XON)                                                  \
    {                                                                         \
        CL_H1(aB0, aB1, aB2, aB3, bB0, bB1, bB2, bB3)                         \
        asm volatile("s_waitcnt vmcnt(4)" ::: "memory");                      \
        aA0 = *(const bf16x8*)(AbR + (BUFOFF));                               \
        aA1 = *(const bf16x8*)(AbR + (BUFOFF) + 1024);                        \
        aA2 = *(const bf16x8*)(AbR + (BUFOFF) + 2048);                        \
        aA3 = *(const bf16x8*)(AbR + (BUFOFF) + 3072);                        \
        gld16(pG, AbW + (BUFOFF));                                            \
        gld16(pG + 1024, AbW + (BUFOFF) + 1024);                              \
        gld16(pG + 2048, AbW + (BUFOFF) + 2048);                              \
        gld16(pG + 3072, AbW + (BUFOFF) + 3072);                              \
        pG += 32768;                                                          \
        LOADB(bA0, bA1, bA2, bA3, bA4, bA5, bA6, XON)                         \
        __builtin_amdgcn_sched_barrier(0);                                    \
        CL_H2(aB0, aB1, aB2, aB3, bB4, bB5, bB6)                              \
    }

// Implicit-GEMM conv, staging directly from x (fused transpose+cvt+swizzle, now
// quad-channel b64 LDS writes), single unified SMEM block, 1-round epilogue.
__global__ __launch_bounds__(512, 2) void conv_kernel(
    const float* __restrict__ x, const __hip_bfloat16* __restrict__ wrt,
    const float* __restrict__ xg, const float* __restrict__ w1,
    const float* __restrict__ b1, float* __restrict__ out) {
    __shared__ __align__(16) char SMEM[159744];
    char* Xs = SMEM;                               // 92160: x-slab (K-loop live)
    char* Ab = SMEM + 92160;                       // 65536: A DMA ring (K-loop live)
    float* hsm = (float*)(SMEM + 157696);          // 2048: h (live whole kernel)
    float* Xf = (float*)SMEM;                      // epilogue: 114688 B over Xs+Ab (dead)
    const int bid = blockIdx.x;
    const int v = (bid & 7) * 28 + (bid >> 3);     // bijective XCD swizzle (224 % 8 == 0)
    const int b = v / 7;
    const int nt = v - b * 7;
    const int tid = threadIdx.x;
    const int lane = tid & 63;
    const int wv = tid >> 6;
    const int mw = wv & 3;
    const int kw2 = wv >> 2;
    const int kcol = lane & 15;
    const int klo = lane >> 4;

    const char* wrtc = (const char*)wrt;
    char* AbW = Ab + wv * 8192;
    const char* AbR = Ab + wv * 8192 + lane * 16;
    const char* pG = wrtc + wv * 4096 + lane * 16;

    // stage A steps 0 -> buf0, 1 -> buf1 (drained by prologue __syncthreads)
    gld16(pG, AbW);
    gld16(pG + 1024, AbW + 1024);
    gld16(pG + 2048, AbW + 2048);
    gld16(pG + 3072, AbW + 3072);
    pG += 32768;
    gld16(pG, AbW + 4096);
    gld16(pG + 1024, AbW + 4096 + 1024);
    gld16(pG + 2048, AbW + 4096 + 2048);
    gld16(pG + 3072, AbW + 4096 + 3072);
    pG += 32768;                                 // next staged step = 2

    // h[j] = sigmoid(xg[b].w1[j] + b1[j])
    {
        float s = b1[tid];
        const float* g = xg + b * 16;
        const float* w = w1 + tid * 16;
#pragma unroll
        for (int c = 0; c < 16; ++c) s += g[c] * w[c];
        hsm[tid] = 1.0f / (1.0f + expf(-s));
    }

    // ---- x-slab staging from x (fp32 NCHW): quad-channel, b64 swizzled writes.
    // Placement identical to the r15-verified layout: position sp, channel ch at
    // sp*512 + ((ch>>3 ^ key(sp))<<4) + (ch&7)*2, key(sp)=(q+4r)&7.
    {
        const bf16x8 z = (bf16x8){0, 0, 0, 0, 0, 0, 0, 0};
        for (int e = tid; e < 6 * 2 * 32; e += 512) {       // pad cols 0/29
            int w = e & 31;
            int t2 = e >> 5;
            int row = t2 >> 1;
            int col = (t2 & 1) ? 29 : 0;
            *(bf16x8*)(Xs + (row * 30 + col) * 512 + w * 16) = z;
        }
        if (nt == 0) {                                       // pad top row
            for (int e = tid; e < 30 * 32; e += 512)
                *(bf16x8*)(Xs + (e >> 5) * 512 + (e & 31) * 16) = z;
        }
        if (nt == 6) {                                       // pad bottom row
            for (int e = tid; e < 30 * 32; e += 512)
                *(bf16x8*)(Xs + (150 + (e >> 5)) * 512 + (e & 31) * 16) = z;
        }
        const int p0 = nt * 4 - 1;
        const float* xb = x + (size_t)b * 256 * 784;
        for (int c = tid; c < 2688; c += 512) {              // 6 rows x 64 ch-quads x 7 c4
            int c4 = c % 7;
            int t2 = c / 7;
            int chq = t2 & 63;
            int row = t2 >> 6;
            int p = p0 + row;
            if (p >= 0 && p < 28) {
                const float* s0 = xb + ((size_t)(chq * 4) * 28 + p) * 28 + 4 * c4;
                f32x4 v0 = *(const f32x4*)(s0);
                f32x4 v1 = *(const f32x4*)(s0 + 784);
                f32x4 v2 = *(const f32x4*)(s0 + 1568);
                f32x4 v3 = *(const f32x4*)(s0 + 2352);
                int w = chq >> 1;
                int qoff = (chq & 1) * 8;
                int spb = row * 30 + 4 * c4 + 1;
#pragma unroll
                for (int k = 0; k < 4; ++k) {
                    int key = (4 * c4 + 1 + k + 4 * row) & 7;
                    union { bf16x4 vv; __hip_bfloat16 e[4]; } pk;
                    pk.e[0] = __float2bfloat16(v0[k]);
                    pk.e[1] = __float2bfloat16(v1[k]);
                    pk.e[2] = __float2bfloat16(v2[k]);
                    pk.e[3] = __float2bfloat16(v3[k]);
                    *(bf16x4*)(Xs + (spb + k) * 512 + (((w ^ key) << 4) | qoff)) = pk.vv;
                }
            }
        }
    }
    __syncthreads();   // drains: A steps 0/1 DMA landed, Xs ready

    unsigned u[7], kk[7];
#pragma unroll
    for (int nf = 0; nf < 7; ++nf) {
        int n = nf * 16 + kcol;
        int r0 = n / 28;
        int q0 = n - r0 * 28;
        u[nf] = (unsigned)((r0 * 30 + q0) * 512 + (klo << 4));
        kk[nf] = (unsigned)(q0 + 4 * r0);
    }
    const unsigned xo0 = (unsigned)((kw2 * 4 + 0) << 6);
    const unsigned xo1 = (unsigned)((kw2 * 4 + 1) << 6);
    const unsigned xo2 = (unsigned)((kw2 * 4 + 2) << 6);
    const unsigned xo3 = (unsigned)((kw2 * 4 + 3) << 6);

    f32x4 acc[4][7];
#pragma unroll
    for (int mf = 0; mf < 4; ++mf)
#pragma unroll
        for (int nf = 0; nf < 7; ++nf) acc[mf][nf] = (f32x4){0.f, 0.f, 0.f, 0.f};

    bf16x8 aA0, aA1, aA2, aA3, aB0, aB1, aB2, aB3;
    bf16x8 bA0, bA1, bA2, bA3, bA4, bA5, bA6;
    bf16x8 bB0, bB1, bB2, bB3, bB4, bB5, bB6;

    // prologue: A(0) from buf0; re-arm buf0 with stage(2); B(0)
    aA0 = *(const bf16x8*)(AbR);
    aA1 = *(const bf16x8*)(AbR + 1024);
    aA2 = *(const bf16x8*)(AbR + 2048);
    aA3 = *(const bf16x8*)(AbR + 3072);
    gld16(pG, AbW);
    gld16(pG + 1024, AbW + 1024);
    gld16(pG + 2048, AbW + 2048);
    gld16(pG + 3072, AbW + 3072);
    pG += 32768;                                 // next staged step = 3
    LOADB(bA0, bA1, bA2, bA3, bA4, bA5, bA6, xo0)

    for (int tap = 0; tap < 9; ++tap) {
        PHASE_E(4096, xo1)
        PHASE_O(0, xo2)
        PHASE_E(4096, xo3)
        if (tap < 8) {
            const int cross = (tap == 2 || tap == 5);
            const unsigned da = cross ? 28u * 512u : 512u;
            const unsigned dk = cross ? 2u : 1u;
#pragma unroll
            for (int nf = 0; nf < 7; ++nf) { u[nf] += da; kk[nf] += dk; }
        }
        PHASE_O(0, xo0)
    }
    // tail stages read dead bytes past wrt (within ws) -- drained below, never consumed.

    // ---- epilogue, single round: Xf spans Xs+Ab (both dead after the barrier drain);
    // hsm (offset 157696) is beyond Xf's 114688 B -- no clash.
    __syncthreads();
    if (kw2 == 1) {
#pragma unroll
        for (int mf = 0; mf < 4; ++mf)
#pragma unroll
            for (int nf = 0; nf < 7; ++nf)
#pragma unroll
                for (int rr = 0; rr < 4; ++rr) {
                    int o = mw * 64 + mf * 16 + klo * 4 + rr;
                    int idx = (((mw * 4 + mf) * 7 + nf) * 4 + rr) * 64 + lane;
                    Xf[idx] = hsm[2 * o + 1] * acc[mf][nf][rr];
                }
    }
    __syncthreads();
    if (kw2 == 0) {
#pragma unroll
        for (int mf = 0; mf < 4; ++mf)
#pragma unroll
            for (int nf = 0; nf < 7; ++nf)
#pragma unroll
                for (int rr = 0; rr < 4; ++rr) {
                    int o = mw * 64 + mf * 16 + klo * 4 + rr;
                    int idx = (((mw * 4 + mf) * 7 + nf) * 4 + rr) * 64 + lane;
                    float y = hsm[2 * o] * acc[mf][nf][rr] + Xf[idx];
                    out[((size_t)b * NO + o) * 784 + nt * 112 + nf * 16 + kcol] = y;
                }
    }
}

extern "C" void kernel_launch(void* const* d_in, const int* in_sizes, int n_in,
                              void* d_out, int out_size, void* d_ws, size_t ws_size,
                              hipStream_t stream) {
    const float* x = (const float*)d_in[0];
    const float* xg = (const float*)d_in[1];
    const float* w1 = (const float*)d_in[2];
    const float* b1 = (const float*)d_in[3];
    const float* w2 = (const float*)d_in[4];
    float* out = (float*)d_out;

    char* ws = (char*)d_ws;
    __hip_bfloat16* wrt = (__hip_bfloat16*)ws;   // 1,179,648 B (A-ring tail overrun reads
                                                 //  land in the unused ws region after it)

    prep_kernel<<<288, 256, 0, stream>>>(w2, wrt);
    conv_kernel<<<224, 512, 0, stream>>>(x, wrt, xg, w1, b1, out);
}